// Round 3
// baseline (251.428 us; speedup 1.0000x reference)
//
#include <hip/hip_runtime.h>

#define EPS_F   0.1f
#define INV_EPS 10.0f
#define NB 16
#define NN 512
#define ND 128
#define MAX_ITER 20
#define BPB 16                                        // blocks per batch
// log(1/512 + 1e-8) computed in fp32 like the reference
#define LOG_MU (-6.2383195f)
#define LOG2E_F 1.4426950408889634f
#define KSC     (INV_EPS * LOG2E_F)                   // scale into log2 domain
#define INVK    (EPS_F * 0.6931471805599453f)         // 1/KSC
#define LM2     (LOG_MU * LOG2E_F)                    // LOG_MU in log2 domain

// Native transcendentals: raw v_exp_f32 / v_log_f32.
#define EXP2(x) __builtin_amdgcn_exp2f(x)
#define LOG2(x) __builtin_amdgcn_logf(x)

#define LD_REL(p)     __hip_atomic_load((p), __ATOMIC_RELAXED, __HIP_MEMORY_SCOPE_AGENT)
#define ST_REL(p, x)  __hip_atomic_store((p), (x), __ATOMIC_RELAXED, __HIP_MEMORY_SCOPE_AGENT)

// Persistent kernel, 256 blocks x 1024 thr (1/CU). bid = 16*bt + b -> all 16
// blocks of batch b land on XCD b%8 (round-robin dispatch heuristic).
//
// R2 REWORK (L3 round trips): R1 showed barrier removal bought only 4% ->
// the per-iteration cost (~6.3us vs 0.8us VALU) is agent-scope (L3
// coherence point) round trips: partial-store drain + flag store + flag
// poll + 64KB combine reads, all serialized. Changes:
//  - DATA-AS-FLAG: col sweep publishes ONE tagged f32 per column
//    (p = m + log2 s, 3 mantissa LSBs replaced by tag ((t>>1)&3)+1).
//    Value and flag are the same word -> no store drain, no flag store,
//    no flag-poll round trip. Double-buffer (t&1) + 2-bit-cycling tag
//    excludes ABA (>=2-iteration skew impossible in a 2-phase exchange).
//  - Combine threads poll their 15 REMOTE slots directly (own partial
//    stays in-register); payload halves (u64 -> u32): 64KB -> 30KB/blk/iter.
//  - errPart gets the same tagging; leader polls it (off critical path).
//  - msPart own-slot zero-init moved in-kernel; one batch-scope
//    barrier_full before the iteration loop orders it rigorously.
// Per iter: 2 __syncthreads + 1 tagged-store/tagged-poll exchange.
//
// Freeze machinery semantics unchanged from the proven design (write-once
// frozenPub[b][t], decision lagged 1 iter; inert for this input: err ~1e4
// >> 1.6 never crosses 0.1*NB in 20 iters, so all blocks run all 20).

// ws float layout
#define WS_ERRPART  0       // 512 = 2(buf) x 16(b) x 16(bt)  (tagged u32 now)
#define WS_ERRB     512     // 320 = errB[t*16+b], init 1e30
#define WS_COSTPART 832     // 256
#define WS_FPUB     1088    // 320 ints: frozenPub[b*20+t], init 0
#define WS_FLAGS    1408    // (unused in R2; kept for layout stability)
#define WS_BARCNT   1920    // 16 x 32 unsigned (128B stride)
#define WS_MSPART   2560    // u32[2][16][16][512] = 1 MB (zeroed in-kernel)
#define WS_TOTAL    2560    // k_zero region

__global__ void k_zero(float* __restrict__ ws) {
    int i = blockIdx.x * 256 + threadIdx.x;
    if (i >= WS_TOTAL) return;
    float val = 0.0f;
    if (i >= WS_ERRB && i < WS_ERRB + 320) val = 1e30f;
    ws[i] = val;                                      // zeros ints/unsigneds too
}

__global__ __launch_bounds__(1024, 4) void
k_sink(const float* __restrict__ x, const float* __restrict__ y,
       float* __restrict__ C, float* __restrict__ pi, float* __restrict__ cost,
       float* errPart, float* errB, float* costPart, int* frozenPub,
       unsigned* flags, unsigned* barCnt, unsigned* msPart) {
    __shared__ float As[128][34];                     // x slice, d-major: As[d][i]
    __shared__ float Bs[32][260];                     // y chunk, k-major: Bs[k][jj]
    __shared__ float xsqS[32];
    __shared__ float ysqS[512];
    __shared__ float vsS[512];                        // v (log2 dom), block-local
    __shared__ float usS[32];                         // u (log2 dom), own stripe
    __shared__ float partS[16];
    __shared__ int flagS;

    (void)flags;
    const int tid = threadIdx.x;
    const int bid = blockIdx.x;
    const int b  = bid & 15;
    const int bt = bid >> 4;                          // 0..15 within batch
    unsigned* cnt = barCnt + b * 32;
    unsigned* errPartU = (unsigned*)errPart;
    unsigned bphase = 0;

    const int w = tid >> 6, l = tid & 63;             // 16 waves

    auto barrier_full = [&](bool flush) {
        ++bphase;
        __syncthreads();
        if (tid == 0) {
            if (flush) __threadfence();
            __hip_atomic_fetch_add(cnt, 1u, __ATOMIC_RELAXED, __HIP_MEMORY_SCOPE_AGENT);
            while (LD_REL(cnt) < BPB * bphase)
                __builtin_amdgcn_s_sleep(1);
        }
        __syncthreads();
    };

    // Zero own msPart slots (tag 0 never matches an expected tag 1..4).
    {
        int zb = tid >> 9, zj = tid & 511;
        ST_REL(msPart + (size_t)zb * 131072 + (size_t)b * 8192 + bt * 512 + zj, 0u);
    }

    // ========== Phase 0: self-contained 32x512 GEMM for own stripe ==========
    const float* xb = x + ((size_t)(b * NN + bt * 32)) * ND;   // own 32 rows
    const float* yb = y + ((size_t)b * NN) * ND;               // all 512 y rows

    for (int r = w; r < 32; r += 16) {
        float a0 = xb[(size_t)r * ND + l], a1 = xb[(size_t)r * ND + l + 64];
        float ss = a0 * a0 + a1 * a1;
#pragma unroll
        for (int off = 32; off; off >>= 1) ss += __shfl_xor(ss, off, 64);
        if (l == 0) xsqS[r] = ss;
    }
    for (int r = w; r < 512; r += 16) {
        float a0 = yb[(size_t)r * ND + l], a1 = yb[(size_t)r * ND + l + 64];
        float ss = a0 * a0 + a1 * a1;
#pragma unroll
        for (int off = 32; off; off >>= 1) ss += __shfl_xor(ss, off, 64);
        if (l == 0) ysqS[r] = ss;
    }
    // Stage A (own 32 rows x 128 d) once, transposed: As[d][i]
    {
        int i = tid >> 5;                             // 0..31
        int dq = (tid & 31) << 2;                     // 0..124
        float4 vx = *(const float4*)(xb + (size_t)i * ND + dq);
        As[dq + 0][i] = vx.x; As[dq + 1][i] = vx.y;
        As[dq + 2][i] = vx.z; As[dq + 3][i] = vx.w;
    }

    // acc[jc][rr][q]: rows 2w+rr, cols jc*256 + 4l + q  == the cR2 layout
    float acc[2][2][4] = {{{0.0f}}};
#pragma unroll
    for (int jc = 0; jc < 2; ++jc) {
        for (int k0 = 0; k0 < ND; k0 += 32) {
            __syncthreads();                          // protect Bs reuse (also A/xsq/ysq 1st time)
            {
                int jj = tid >> 3;                    // 0..127
                int kq = (tid & 7) << 2;              // 0..28
                const float* ybase = yb + (size_t)(jc * 256) * ND + k0 + kq;
                float4 v0 = *(const float4*)(ybase + (size_t)jj * ND);
                float4 v1 = *(const float4*)(ybase + (size_t)(jj + 128) * ND);
                Bs[kq + 0][jj] = v0.x; Bs[kq + 1][jj] = v0.y;
                Bs[kq + 2][jj] = v0.z; Bs[kq + 3][jj] = v0.w;
                Bs[kq + 0][jj + 128] = v1.x; Bs[kq + 1][jj + 128] = v1.y;
                Bs[kq + 2][jj + 128] = v1.z; Bs[kq + 3][jj + 128] = v1.w;
            }
            __syncthreads();
#pragma unroll
            for (int k = 0; k < 32; ++k) {
                float2 av = *(const float2*)&As[k0 + k][2 * w];   // broadcast
                float4 bv = *(const float4*)&Bs[k][4 * l];
                acc[jc][0][0] += av.x * bv.x;
                acc[jc][0][1] += av.x * bv.y;
                acc[jc][0][2] += av.x * bv.z;
                acc[jc][0][3] += av.x * bv.w;
                acc[jc][1][0] += av.y * bv.x;
                acc[jc][1][1] += av.y * bv.y;
                acc[jc][1][2] += av.y * bv.z;
                acc[jc][1][3] += av.y * bv.w;
            }
        }
    }

    // Epilogue: write C stripe + build cR2 in place (log2 dom, scaled by KSC)
    float4 cR2[2][2];
    float* Cb = C + ((size_t)(b * NN + bt * 32)) * NN;
    {
        float4 ys0 = *(const float4*)&ysqS[4 * l];
        float4 ys1 = *(const float4*)&ysqS[256 + 4 * l];
#pragma unroll
        for (int rr = 0; rr < 2; ++rr) {
            float xq = xsqS[2 * w + rr];
            float4 o0, o1;
            o0.x = xq + ys0.x - 2.0f * acc[0][rr][0];
            o0.y = xq + ys0.y - 2.0f * acc[0][rr][1];
            o0.z = xq + ys0.z - 2.0f * acc[0][rr][2];
            o0.w = xq + ys0.w - 2.0f * acc[0][rr][3];
            o1.x = xq + ys1.x - 2.0f * acc[1][rr][0];
            o1.y = xq + ys1.y - 2.0f * acc[1][rr][1];
            o1.z = xq + ys1.z - 2.0f * acc[1][rr][2];
            o1.w = xq + ys1.w - 2.0f * acc[1][rr][3];
            float* Crow = Cb + (size_t)(2 * w + rr) * NN;
            *(float4*)(Crow + 4 * l) = o0;
            *(float4*)(Crow + 256 + 4 * l) = o1;
            cR2[rr][0].x = o0.x * KSC; cR2[rr][0].y = o0.y * KSC;
            cR2[rr][0].z = o0.z * KSC; cR2[rr][0].w = o0.w * KSC;
            cR2[rr][1].x = o1.x * KSC; cR2[rr][1].y = o1.y * KSC;
            cR2[rr][1].z = o1.z * KSC; cR2[rr][1].w = o1.w * KSC;
        }
    }
    __syncthreads();                                  // own C stripe drained + block-visible

    // cC2: full transposed col-cache from OWN stripe (same-CU readback)
    float cC2[32];                                    // col j=tid, all 32 local rows
    if (tid < 512) {
        const float* Cc = Cb + tid;
#pragma unroll
        for (int r = 0; r < 32; ++r) cC2[r] = Cc[(size_t)r * NN] * KSC;
    }

    // Batch-scope barrier: all 16 blocks' msPart zero-stores complete before
    // anyone can poll them (rigorous init ordering, one-time cost).
    barrier_full(false);

    // ================= Sinkhorn iterations =================
    if (tid < 512) vsS[tid] = 0.0f;
    if (tid == 0)  flagS = 0;
    __syncthreads();
    float uPrev[2] = {0.0f, 0.0f};                    // log2-domain u, own rows
    int frozenLatch = 0;

    for (int t = 0; t < MAX_ITER; ++t) {
        if (flagS) break;                             // uniform (lagged decision)
        const int buf = t & 1;
        const unsigned expTag = ((unsigned)(t >> 1) & 3u) + 1u;   // 1..4 cycle

        // ---- ROW sweep (log2 domain): u for own 2 rows/wave ----
        float4 v0 = *(const float4*)(vsS + 4 * l);
        float4 v1 = *(const float4*)(vsS + 256 + 4 * l);
        float duSum = 0.0f, unArr[2];
#pragma unroll
        for (int rr = 0; rr < 2; ++rr) {
            float4 c0 = cR2[rr][0], c1 = cR2[rr][1];
            float tv[8] = {v0.x - c0.x, v0.y - c0.y, v0.z - c0.z, v0.w - c0.w,
                           v1.x - c1.x, v1.y - c1.y, v1.z - c1.z, v1.w - c1.w};
            float m = tv[0];
#pragma unroll
            for (int k = 1; k < 8; ++k) m = fmaxf(m, tv[k]);
#pragma unroll
            for (int off = 32; off; off >>= 1)        // max first: no exps in shfl
                m = fmaxf(m, __shfl_xor(m, off, 64));
            float s = 0.0f;
#pragma unroll
            for (int k = 0; k < 8; ++k) s += EXP2(tv[k] - m);
#pragma unroll
            for (int off = 32; off; off >>= 1) s += __shfl_xor(s, off, 64);
            float un = LM2 - (m + LOG2(s));           // u in log2 domain
            unArr[rr] = un;
            duSum += fabsf(un - uPrev[rr]);
            uPrev[rr] = un;
        }
        if (l == 0) {
            usS[w * 2 + 0] = unArr[0];
            usS[w * 2 + 1] = unArr[1];
            partS[w] = duSum;
        }
        __syncthreads();                              // A: usS + partS ready

        // tid0: publish tagged err partial ASAP (leader consumes off-path)
        if (tid == 0) {
            float e = 0.0f;
#pragma unroll
            for (int q = 0; q < 16; ++q) e += partS[q];
            unsigned ebits = (__float_as_uint(e * INVK) & ~7u) | expTag;
            ST_REL(errPartU + buf * 256 + b * 16 + bt, ebits);
        }

        // ---- COL sweep: thread j < 512 does all 32 rows, publishes tagged f32 ----
        float pSelf = 0.0f;
        if (tid < 512) {
            float tvc[32];
#pragma unroll
            for (int r = 0; r < 32; ++r) tvc[r] = usS[r] - cC2[r];
            float m = tvc[0];
#pragma unroll
            for (int r = 1; r < 32; ++r) m = fmaxf(m, tvc[r]);
            float s = 0.0f;
#pragma unroll
            for (int r = 0; r < 32; ++r) s += EXP2(tvc[r] - m);
            float p = m + LOG2(s);                    // partial LSE, log2 domain
            unsigned bits = (__float_as_uint(p) & ~7u) | expTag;
            pSelf = __uint_as_float(bits);            // use remote-visible value
            ST_REL(msPart + (size_t)buf * 131072 + (size_t)b * 8192 + bt * 512 + tid, bits);
        }

        if (tid == 0 && t >= 1)                       // slot t-1: write-once, ordered
            flagS = LD_REL(frozenPub + b * 20 + (t - 1));

        // ---- POLL + COMBINE: 15 remote tagged slots, own kept in-register ----
        if (tid < 512) {
            float pv[16];
#pragma unroll
            for (int q = 0; q < 16; ++q) pv[q] = pSelf;
            unsigned need = 0xffffu & ~(1u << bt);
            const unsigned* mpBase = msPart + (size_t)buf * 131072 + (size_t)b * 8192 + tid;
            while (need) {
#pragma unroll
                for (int q = 0; q < 16; ++q) {
                    if (need & (1u << q)) {
                        unsigned r = LD_REL(mpBase + (size_t)q * 512);
                        if ((r & 7u) == expTag) {
                            pv[q] = __uint_as_float(r);
                            need &= ~(1u << q);
                        }
                    }
                }
                if (need) __builtin_amdgcn_s_sleep(1);
            }
            float mm = pv[0];
#pragma unroll
            for (int q = 1; q < 16; ++q) mm = fmaxf(mm, pv[q]);
            float ss = 0.0f;
#pragma unroll
            for (int q = 0; q < 16; ++q) ss += EXP2(pv[q] - mm);
            vsS[tid] = LM2 - (mm + LOG2(ss));         // v in log2 domain
        }

        // leader wave (idle otherwise): err bookkeeping + decision(t) -> slot t
        if (bt == 0 && w == 15) {
            float e = 0.0f;
            if (l < 16) {
                unsigned r;
                for (;;) {
                    r = LD_REL(errPartU + buf * 256 + b * 16 + l);
                    if ((r & 7u) == expTag) break;
                    __builtin_amdgcn_s_sleep(1);
                }
                e = __uint_as_float(r);
            }
#pragma unroll
            for (int off = 8; off; off >>= 1) e += __shfl_xor(e, off, 64);
            if (l == 0) ST_REL(errB + t * 16 + b, e);
            float g = (l < 16) ? ((l == b) ? e : LD_REL(errB + t * 16 + l)) : 0.0f;
#pragma unroll
            for (int off = 8; off; off >>= 1) g += __shfl_xor(g, off, 64);
            g = __shfl(g, 0, 64);
            frozenLatch |= (g < 0.1f * NB) ? 1 : 0;   // wave-uniform
            if (l == 0) ST_REL(frozenPub + b * 20 + t, frozenLatch);
        }
        __syncthreads();                              // E: vsS + flagS ready
    }

    // ===== PI phase (log2 dom): p = 2^(u2+v2-c2); cost = sum p*c2 / KSC =====
    float csum = 0.0f;
    {
        float4 v0 = *(const float4*)(vsS + 4 * l);
        float4 v1 = *(const float4*)(vsS + 256 + 4 * l);
#pragma unroll
        for (int rr = 0; rr < 2; ++rr) {
            int i = bt * 32 + w * 2 + rr;
            float uu = uPrev[rr];
            float* prow = pi + ((size_t)(b * NN + i)) * NN;
            float4 c0 = cR2[rr][0], c1 = cR2[rr][1];
            float4 p0, p1;
            p0.x = EXP2(uu + v0.x - c0.x);
            p0.y = EXP2(uu + v0.y - c0.y);
            p0.z = EXP2(uu + v0.z - c0.z);
            p0.w = EXP2(uu + v0.w - c0.w);
            p1.x = EXP2(uu + v1.x - c1.x);
            p1.y = EXP2(uu + v1.y - c1.y);
            p1.z = EXP2(uu + v1.z - c1.z);
            p1.w = EXP2(uu + v1.w - c1.w);
            *(float4*)(prow + 4 * l) = p0;
            *(float4*)(prow + 256 + 4 * l) = p1;
            csum += p0.x * c0.x + p0.y * c0.y + p0.z * c0.z + p0.w * c0.w +
                    p1.x * c1.x + p1.y * c1.y + p1.z * c1.z + p1.w * c1.w;
        }
    }
#pragma unroll
    for (int off = 32; off; off >>= 1) csum += __shfl_xor(csum, off, 64);
    if (l == 0) partS[w] = csum;
    __syncthreads();
    if (tid == 0) {
        float s = 0.0f;
#pragma unroll
        for (int q = 0; q < 16; ++q) s += partS[q];
        ST_REL(costPart + b * 16 + bt, s * INVK);     // back to raw-C domain
    }
    barrier_full(false);                              // cost partials visible
    if (bt == 0 && tid == 0) {
        float s = 0.0f;
        for (int q = 0; q < 16; ++q) s += LD_REL(costPart + b * 16 + q);
        cost[b] = s;                                  // plain store; kernel-end release
    }
}

extern "C" void kernel_launch(void* const* d_in, const int* in_sizes, int n_in,
                              void* d_out, int out_size, void* d_ws, size_t ws_size,
                              hipStream_t stream) {
    const float* x = (const float*)d_in[0];
    const float* y = (const float*)d_in[1];

    // Output layout: cost[16], pi[16*512*512], C[16*512*512]
    float* cost = (float*)d_out;
    float* pi   = cost + 16;
    float* C    = pi + (size_t)NB * NN * NN;

    float* f = (float*)d_ws;
    float* errPart  = f + WS_ERRPART;
    float* errB     = f + WS_ERRB;
    float* costPart = f + WS_COSTPART;
    int*   frozenPub = (int*)(f + WS_FPUB);
    unsigned* flags  = (unsigned*)(f + WS_FLAGS);
    unsigned* barCnt = (unsigned*)(f + WS_BARCNT);
    unsigned* msPart = (unsigned*)(f + WS_MSPART);

    hipLaunchKernelGGL(k_zero, dim3((WS_TOTAL + 255) / 256), dim3(256), 0, stream, f);

    void* args[] = {(void*)&x, (void*)&y, (void*)&C, (void*)&pi, (void*)&cost,
                    (void*)&errPart, (void*)&errB, (void*)&costPart,
                    (void*)&frozenPub, (void*)&flags, (void*)&barCnt, (void*)&msPart};
    hipError_t e = hipLaunchCooperativeKernel((const void*)k_sink, dim3(256), dim3(1024),
                                              args, 0, stream);
    if (e != hipSuccess) {
        // Fallback: plain launch. 256 blocks x 1024 thr, 1 block/CU -> co-resident.
        hipLaunchKernelGGL(k_sink, dim3(256), dim3(1024), 0, stream,
                           x, y, C, pi, cost, errPart, errB, costPart,
                           frozenPub, flags, barCnt, msPart);
    }
}

// Round 5
// 234.027 us; speedup vs baseline: 1.0744x; 1.0744x over previous
//
#include <hip/hip_runtime.h>

#define EPS_F   0.1f
#define INV_EPS 10.0f
#define NB 16
#define NN 512
#define ND 128
#define MAX_ITER 20
#define BPB 16                                        // blocks per batch
// log(1/512 + 1e-8) computed in fp32 like the reference
#define LOG_MU (-6.2383195f)
#define LOG2E_F 1.4426950408889634f
#define KSC     (INV_EPS * LOG2E_F)                   // scale into log2 domain
#define INVK    (EPS_F * 0.6931471805599453f)         // 1/KSC
#define LM2     (LOG_MU * LOG2E_F)                    // LOG_MU in log2 domain

// Native transcendentals: raw v_exp_f32 / v_log_f32.
#define EXP2(x) __builtin_amdgcn_exp2f(x)
#define LOG2(x) __builtin_amdgcn_logf(x)

#define LD_REL(p)     __hip_atomic_load((p), __ATOMIC_RELAXED, __HIP_MEMORY_SCOPE_AGENT)
#define ST_REL(p, x)  __hip_atomic_store((p), (x), __ATOMIC_RELAXED, __HIP_MEMORY_SCOPE_AGENT)

// Persistent kernel, 257 blocks x 1024 thr. bid<256: main (bid=16*bt+b);
// bid==256: global err/freeze leader (1 wave; shares a CU, mostly sleeping).
//
// R4 = R3 resubmitted verbatim (R3 bench was an infra/container failure, no
// measurement). Deadlock audit: 55KB LDS -> 2 blocks/CU capacity, so all 257
// blocks co-resident even under the plain fallback launch; leader waits only
// on slots every main block is guaranteed to publish (incl. dummy publishes
// on freeze-break); frozenPub is monotone and sampled at a fixed lag -> all
// blocks break at the same t; k_zero re-inits all flags each replay; msPart
// is flag-gated so stale contents are never read.
//
// R3 THEORY (unmeasured): R2 showed data-as-flag polling (512 thr x 15
// scattered slots) regressed (158->173us) -- poll TRAFFIC, not round-trip
// count, is the cost. R3: (a) proven flag-then-bulk-combine exchange (poll =
// 8 waves x one 64B flag line), u32 payload (p = m + log2 s, untagged,
// flag-gated); (b) err/freeze moved OFF main blocks to the 257th leader
// block (write-once errPart[t][b][bt], ready bit = mantissa LSB); main
// blocks publish fire-and-forget and read frozenPub[t-1] overlapped with
// the combine. Freeze semantics = proven lagged design (inert here: err
// ~1e4 >> 1.6 never crosses 0.1*NB).

// ws u32/float layout
#define WS_ERRPART  0       // 5120 u32: [t][b*16+bt], write-once, LSB=ready
#define WS_FPUB     5120    // 32 ints: frozenPub[t]
#define WS_FLAGS    5152    // 256 u32: flags[b*16+bt] (64B line per batch)
#define WS_BARCNT   5408    // 512 u32: barCnt[b*32] (128B stride)
#define WS_COSTPART 5920    // 256 f32
#define WS_MSPART   6176    // u32[2][16][16][512] = 262144 (flag-gated, no init)
#define WS_TOTAL    6176    // zeroed region

__global__ void k_zero(float* __restrict__ ws) {
    int i = blockIdx.x * 256 + threadIdx.x;
    if (i >= WS_TOTAL) return;
    ws[i] = 0.0f;                                     // zeros ints/unsigneds too
}

__global__ __launch_bounds__(1024, 4) void
k_sink(const float* __restrict__ x, const float* __restrict__ y,
       float* __restrict__ C, float* __restrict__ pi, float* __restrict__ cost,
       unsigned* errPartU, float* costPart, int* frozenPub,
       unsigned* flags, unsigned* barCnt, unsigned* msPart) {
    const int tid = threadIdx.x;
    const int bid = blockIdx.x;

    // ================= Global leader block: err reduce + freeze =================
    if (bid == 256) {
        if (tid >= 64) return;                        // 1 wave; no __syncthreads here
        const int l = tid;
        int frozen = 0;
        for (int t = 0; t < MAX_ITER; ++t) {
            float e = 0.0f;
#pragma unroll
            for (int k = 0; k < 4; ++k) {             // 4 slots/lane = 256 slots
                const unsigned* slot = errPartU + t * 256 + k * 64 + l;
                unsigned r;
                for (;;) {
                    r = LD_REL(slot);
                    if (r & 1u) break;                // ready bit
                    __builtin_amdgcn_s_sleep(1);
                }
                e += __uint_as_float(r & ~1u);
            }
#pragma unroll
            for (int off = 32; off; off >>= 1) e += __shfl_xor(e, off, 64);
            frozen |= (e < 0.1f * NB) ? 1 : 0;        // global mean err < thresh
            if (l == 0) ST_REL(frozenPub + t, frozen);
        }
        return;
    }

    __shared__ float As[128][34];                     // x slice, d-major: As[d][i]
    __shared__ float Bs[32][260];                     // y chunk, k-major: Bs[k][jj]
    __shared__ float xsqS[32];
    __shared__ float ysqS[512];
    __shared__ float vsS[512];                        // v (log2 dom), block-local
    __shared__ float usS[32];                         // u (log2 dom), own stripe
    __shared__ float partS[16];
    __shared__ int flagS;

    const int b  = bid & 15;
    const int bt = bid >> 4;                          // 0..15 within batch
    unsigned* cnt = barCnt + b * 32;
    unsigned* flagsB = flags + b * 16;                // 16 u32 = one 64B line
    unsigned bphase = 0;

    const int w = tid >> 6, l = tid & 63;             // 16 waves

    auto barrier_full = [&]() {
        ++bphase;
        __syncthreads();
        if (tid == 0) {
            __hip_atomic_fetch_add(cnt, 1u, __ATOMIC_RELAXED, __HIP_MEMORY_SCOPE_AGENT);
            while (LD_REL(cnt) < BPB * bphase)
                __builtin_amdgcn_s_sleep(1);
        }
        __syncthreads();
    };

    // ========== Phase 0: self-contained 32x512 GEMM for own stripe ==========
    const float* xb = x + ((size_t)(b * NN + bt * 32)) * ND;   // own 32 rows
    const float* yb = y + ((size_t)b * NN) * ND;               // all 512 y rows

    for (int r = w; r < 32; r += 16) {
        float a0 = xb[(size_t)r * ND + l], a1 = xb[(size_t)r * ND + l + 64];
        float ss = a0 * a0 + a1 * a1;
#pragma unroll
        for (int off = 32; off; off >>= 1) ss += __shfl_xor(ss, off, 64);
        if (l == 0) xsqS[r] = ss;
    }
    for (int r = w; r < 512; r += 16) {
        float a0 = yb[(size_t)r * ND + l], a1 = yb[(size_t)r * ND + l + 64];
        float ss = a0 * a0 + a1 * a1;
#pragma unroll
        for (int off = 32; off; off >>= 1) ss += __shfl_xor(ss, off, 64);
        if (l == 0) ysqS[r] = ss;
    }
    // Stage A (own 32 rows x 128 d) once, transposed: As[d][i]
    {
        int i = tid >> 5;                             // 0..31
        int dq = (tid & 31) << 2;                     // 0..124
        float4 vx = *(const float4*)(xb + (size_t)i * ND + dq);
        As[dq + 0][i] = vx.x; As[dq + 1][i] = vx.y;
        As[dq + 2][i] = vx.z; As[dq + 3][i] = vx.w;
    }

    // acc[jc][rr][q]: rows 2w+rr, cols jc*256 + 4l + q  == the cR2 layout
    float acc[2][2][4] = {{{0.0f}}};
#pragma unroll
    for (int jc = 0; jc < 2; ++jc) {
        for (int k0 = 0; k0 < ND; k0 += 32) {
            __syncthreads();                          // protect Bs reuse (also A/xsq/ysq 1st time)
            {
                int jj = tid >> 3;                    // 0..127
                int kq = (tid & 7) << 2;              // 0..28
                const float* ybase = yb + (size_t)(jc * 256) * ND + k0 + kq;
                float4 v0 = *(const float4*)(ybase + (size_t)jj * ND);
                float4 v1 = *(const float4*)(ybase + (size_t)(jj + 128) * ND);
                Bs[kq + 0][jj] = v0.x; Bs[kq + 1][jj] = v0.y;
                Bs[kq + 2][jj] = v0.z; Bs[kq + 3][jj] = v0.w;
                Bs[kq + 0][jj + 128] = v1.x; Bs[kq + 1][jj + 128] = v1.y;
                Bs[kq + 2][jj + 128] = v1.z; Bs[kq + 3][jj + 128] = v1.w;
            }
            __syncthreads();
#pragma unroll
            for (int k = 0; k < 32; ++k) {
                float2 av = *(const float2*)&As[k0 + k][2 * w];   // broadcast
                float4 bv = *(const float4*)&Bs[k][4 * l];
                acc[jc][0][0] += av.x * bv.x;
                acc[jc][0][1] += av.x * bv.y;
                acc[jc][0][2] += av.x * bv.z;
                acc[jc][0][3] += av.x * bv.w;
                acc[jc][1][0] += av.y * bv.x;
                acc[jc][1][1] += av.y * bv.y;
                acc[jc][1][2] += av.y * bv.z;
                acc[jc][1][3] += av.y * bv.w;
            }
        }
    }

    // Epilogue: write C stripe + build cR2 in place (log2 dom, scaled by KSC)
    float4 cR2[2][2];
    float* Cb = C + ((size_t)(b * NN + bt * 32)) * NN;
    {
        float4 ys0 = *(const float4*)&ysqS[4 * l];
        float4 ys1 = *(const float4*)&ysqS[256 + 4 * l];
#pragma unroll
        for (int rr = 0; rr < 2; ++rr) {
            float xq = xsqS[2 * w + rr];
            float4 o0, o1;
            o0.x = xq + ys0.x - 2.0f * acc[0][rr][0];
            o0.y = xq + ys0.y - 2.0f * acc[0][rr][1];
            o0.z = xq + ys0.z - 2.0f * acc[0][rr][2];
            o0.w = xq + ys0.w - 2.0f * acc[0][rr][3];
            o1.x = xq + ys1.x - 2.0f * acc[1][rr][0];
            o1.y = xq + ys1.y - 2.0f * acc[1][rr][1];
            o1.z = xq + ys1.z - 2.0f * acc[1][rr][2];
            o1.w = xq + ys1.w - 2.0f * acc[1][rr][3];
            float* Crow = Cb + (size_t)(2 * w + rr) * NN;
            *(float4*)(Crow + 4 * l) = o0;
            *(float4*)(Crow + 256 + 4 * l) = o1;
            cR2[rr][0].x = o0.x * KSC; cR2[rr][0].y = o0.y * KSC;
            cR2[rr][0].z = o0.z * KSC; cR2[rr][0].w = o0.w * KSC;
            cR2[rr][1].x = o1.x * KSC; cR2[rr][1].y = o1.y * KSC;
            cR2[rr][1].z = o1.z * KSC; cR2[rr][1].w = o1.w * KSC;
        }
    }
    __syncthreads();                                  // own C stripe drained + block-visible

    // cC2: full transposed col-cache from OWN stripe (same-CU readback)
    float cC2[32];                                    // col j=tid, all 32 local rows
    if (tid < 512) {
        const float* Cc = Cb + tid;
#pragma unroll
        for (int r = 0; r < 32; ++r) cC2[r] = Cc[(size_t)r * NN] * KSC;
    }

    // ================= Sinkhorn iterations =================
    if (tid < 512) vsS[tid] = 0.0f;
    if (tid == 0)  flagS = 0;
    __syncthreads();
    float uPrev[2] = {0.0f, 0.0f};                    // log2-domain u, own rows

    for (int t = 0; t < MAX_ITER; ++t) {
        if (flagS) {                                  // frozen (lagged decision)
            if (tid == 0)                             // unblock leader for rest
                for (int tt = t; tt < MAX_ITER; ++tt)
                    ST_REL(errPartU + tt * 256 + b * 16 + bt, 1u);
            break;
        }
        const int buf = t & 1;

        // ---- ROW sweep (log2 domain): u for own 2 rows/wave ----
        float4 v0 = *(const float4*)(vsS + 4 * l);
        float4 v1 = *(const float4*)(vsS + 256 + 4 * l);
        float duSum = 0.0f, unArr[2];
#pragma unroll
        for (int rr = 0; rr < 2; ++rr) {
            float4 c0 = cR2[rr][0], c1 = cR2[rr][1];
            float tv[8] = {v0.x - c0.x, v0.y - c0.y, v0.z - c0.z, v0.w - c0.w,
                           v1.x - c1.x, v1.y - c1.y, v1.z - c1.z, v1.w - c1.w};
            float m = tv[0];
#pragma unroll
            for (int k = 1; k < 8; ++k) m = fmaxf(m, tv[k]);
#pragma unroll
            for (int off = 32; off; off >>= 1)        // max first: no exps in shfl
                m = fmaxf(m, __shfl_xor(m, off, 64));
            float s = 0.0f;
#pragma unroll
            for (int k = 0; k < 8; ++k) s += EXP2(tv[k] - m);
#pragma unroll
            for (int off = 32; off; off >>= 1) s += __shfl_xor(s, off, 64);
            float un = LM2 - (m + LOG2(s));           // u in log2 domain
            unArr[rr] = un;
            duSum += fabsf(un - uPrev[rr]);
            uPrev[rr] = un;
        }
        if (l == 0) {
            usS[w * 2 + 0] = unArr[0];
            usS[w * 2 + 1] = unArr[1];
            partS[w] = duSum;
        }
        __syncthreads();                              // A: usS + partS ready

        // tid0: publish err partial, fire-and-forget (leader block consumes)
        if (tid == 0) {
            float e = 0.0f;
#pragma unroll
            for (int q = 0; q < 16; ++q) e += partS[q];
            unsigned ebits = (__float_as_uint(e * INVK) & ~1u) | 1u;
            ST_REL(errPartU + t * 256 + b * 16 + bt, ebits);
        }

        // ---- COL sweep: thread j < 512 does all 32 rows, publishes p_j ----
        if (tid < 512) {
            float tvc[32];
#pragma unroll
            for (int r = 0; r < 32; ++r) tvc[r] = usS[r] - cC2[r];
            float m = tvc[0];
#pragma unroll
            for (int r = 1; r < 32; ++r) m = fmaxf(m, tvc[r]);
            float s = 0.0f;
#pragma unroll
            for (int r = 0; r < 32; ++r) s += EXP2(tvc[r] - m);
            float p = m + LOG2(s);                    // partial LSE, log2 domain
            ST_REL(msPart + (size_t)buf * 131072 + (size_t)b * 8192 + bt * 512 + tid,
                   __float_as_uint(p));
        }
        __syncthreads();                              // B: publishes drained
        if (tid == 0) {
            ST_REL(flagsB + bt, (unsigned)(t + 1));
            if (t >= 1)                               // overlapped with poll/combine
                flagS = LD_REL(frozenPub + (t - 1));
        }

        // ---- POLL (8 combine waves, one 64B line) + bulk COMBINE ----
        if (w < 8) {
            const unsigned tgt = (unsigned)(t + 1);
            for (;;) {
                unsigned fv = (l < 16) ? LD_REL(flagsB + l) : tgt;
                if (__all(fv >= tgt)) break;
                __builtin_amdgcn_s_sleep(1);
            }
            // tid < 512 guaranteed: merge 16 stripe partials -> v_j
            size_t base = (size_t)buf * 131072 + (size_t)b * 8192 + tid;
            float pv[16];
#pragma unroll
            for (int q = 0; q < 16; ++q)
                pv[q] = __uint_as_float(LD_REL(msPart + base + (size_t)q * 512));
            float mm = pv[0];
#pragma unroll
            for (int q = 1; q < 16; ++q) mm = fmaxf(mm, pv[q]);
            float ss = 0.0f;
#pragma unroll
            for (int q = 0; q < 16; ++q) ss += EXP2(pv[q] - mm);
            vsS[tid] = LM2 - (mm + LOG2(ss));         // v in log2 domain
        }
        __syncthreads();                              // E: vsS + flagS ready
    }

    // ===== PI phase (log2 dom): p = 2^(u2+v2-c2); cost = sum p*c2 / KSC =====
    float csum = 0.0f;
    {
        float4 v0 = *(const float4*)(vsS + 4 * l);
        float4 v1 = *(const float4*)(vsS + 256 + 4 * l);
#pragma unroll
        for (int rr = 0; rr < 2; ++rr) {
            int i = bt * 32 + w * 2 + rr;
            float uu = uPrev[rr];
            float* prow = pi + ((size_t)(b * NN + i)) * NN;
            float4 c0 = cR2[rr][0], c1 = cR2[rr][1];
            float4 p0, p1;
            p0.x = EXP2(uu + v0.x - c0.x);
            p0.y = EXP2(uu + v0.y - c0.y);
            p0.z = EXP2(uu + v0.z - c0.z);
            p0.w = EXP2(uu + v0.w - c0.w);
            p1.x = EXP2(uu + v1.x - c1.x);
            p1.y = EXP2(uu + v1.y - c1.y);
            p1.z = EXP2(uu + v1.z - c1.z);
            p1.w = EXP2(uu + v1.w - c1.w);
            *(float4*)(prow + 4 * l) = p0;
            *(float4*)(prow + 256 + 4 * l) = p1;
            csum += p0.x * c0.x + p0.y * c0.y + p0.z * c0.z + p0.w * c0.w +
                    p1.x * c1.x + p1.y * c1.y + p1.z * c1.z + p1.w * c1.w;
        }
    }
#pragma unroll
    for (int off = 32; off; off >>= 1) csum += __shfl_xor(csum, off, 64);
    if (l == 0) partS[w] = csum;
    __syncthreads();
    if (tid == 0) {
        float s = 0.0f;
#pragma unroll
        for (int q = 0; q < 16; ++q) s += partS[q];
        ST_REL(costPart + b * 16 + bt, s * INVK);     // back to raw-C domain
    }
    barrier_full();                                   // cost partials visible
    if (bt == 0 && tid == 0) {
        float s = 0.0f;
        for (int q = 0; q < 16; ++q) s += LD_REL(costPart + b * 16 + q);
        cost[b] = s;                                  // plain store; kernel-end release
    }
}

extern "C" void kernel_launch(void* const* d_in, const int* in_sizes, int n_in,
                              void* d_out, int out_size, void* d_ws, size_t ws_size,
                              hipStream_t stream) {
    const float* x = (const float*)d_in[0];
    const float* y = (const float*)d_in[1];

    // Output layout: cost[16], pi[16*512*512], C[16*512*512]
    float* cost = (float*)d_out;
    float* pi   = cost + 16;
    float* C    = pi + (size_t)NB * NN * NN;

    float* f = (float*)d_ws;
    unsigned* errPartU = (unsigned*)(f + WS_ERRPART);
    int*   frozenPub = (int*)(f + WS_FPUB);
    unsigned* flags  = (unsigned*)(f + WS_FLAGS);
    unsigned* barCnt = (unsigned*)(f + WS_BARCNT);
    float* costPart  = f + WS_COSTPART;
    unsigned* msPart = (unsigned*)(f + WS_MSPART);

    hipLaunchKernelGGL(k_zero, dim3((WS_TOTAL + 255) / 256), dim3(256), 0, stream, f);

    void* args[] = {(void*)&x, (void*)&y, (void*)&C, (void*)&pi, (void*)&cost,
                    (void*)&errPartU, (void*)&costPart, (void*)&frozenPub,
                    (void*)&flags, (void*)&barCnt, (void*)&msPart};
    hipError_t e = hipLaunchCooperativeKernel((const void*)k_sink, dim3(257), dim3(1024),
                                              args, 0, stream);
    if (e != hipSuccess) {
        // Fallback: plain launch. 257 blocks x 1024 thr, <=2/CU -> co-resident.
        hipLaunchKernelGGL(k_sink, dim3(257), dim3(1024), 0, stream,
                           x, y, C, pi, cost, errPartU, costPart,
                           frozenPub, flags, barCnt, msPart);
    }
}